// Round 3
// baseline (92.995 us; speedup 1.0000x reference)
//
#include <hip/hip_runtime.h>
#include <math.h>

// ExtrudeNet fused kernels for MI355X (gfx950) — round 3.
// B=4, M=2048 points, K=64 primitives, C=64, NSEG=4, SAMPLE_RATE=16 -> S=64 curve samples.
// Inputs (float32): pts (B,M,3), pp (B,28,K), Wint (B,K,C), Uw (B,C), is_training (int, always 1).
// Output (float32, concatenated): occupancies (B,M) | primitive_sdf (B,M,K) | inter (B,M,C) | support (B,M,K).
//
// R3 changes vs R2 (R2 kernel ~42 us inferred; R1 counters: VALUBusy 97%, Occupancy 35%):
//  - curve table (depends only on batch, 32 KB x 4) precomputed once by kernel A into d_ws;
//    main kernel stages it with a float4 copy instead of recomputing per block (~20% VALU cut).
//  - 512-thread blocks (8 pts/block): 4 blocks x 8 waves x 34 KB LDS = 32 waves/CU (max occupancy),
//    grid 1024 = exactly 4 blocks/CU, no tail round. __launch_bounds__(512,8) caps VGPR at 64.
//  - phase-1 loop linearized (s=1..63 + register-carried wrap edge): ds_read_b64 with immediate
//    offsets, no per-iter address VALU; carried sign flag saves 1 cmp/iter; dual min/wn accumulators.
//  - rsqf/rcpf for quaternion norm, sigmoid, softmax divisions (1-ulp, well under threshold).

#define NB 4
#define NM 2048
#define NK 64
#define NC 64
#define NS 64
#define PPB 8   // points per 512-thread block (1 wave per point)

// Offsets into flat output
#define OCC_OFF   0
#define SDF_OFF   8192        // NB*NM
#define INTER_OFF 532480      // 8192 + 524288
#define SUP_OFF   1056768     // 8192 + 2*524288

// theta = 2*pi/16 + atan(tan(2*pi/16)/3) = 0.5299027864949896 (double-accurate)
#define CT 0.86285621096f     // cos(theta)
#define ST 0.50544946275f     // sin(theta)

#define L2E_40  57.70780163555852f   // 40 * log2(e)
#define L2E_150 216.40425613334447f  // 150 * log2(e)

// ---------- Kernel A: per-batch rational-bezier curve tables into workspace ----------
// grid = 4 (one block per batch), block = 256 (wave = segment, lane = primitive k).
__global__ __launch_bounds__(256) void curve_table_kernel(
    const float* __restrict__ pp,
    float2* __restrict__ wcurve)   // [NB][NS][NK]
{
    const int b    = blockIdx.x;
    const int lane = threadIdx.x & 63;
    const int seg  = threadIdx.x >> 6;          // 0..3
    const int nseg = (seg + 1) & 3;
    const float* __restrict__ ppb = pp + b * (28 * NK);
    const int k = lane;

    const float r0 = fabsf(ppb[(8 + seg * 3 + 0) * NK + k]);
    const float r1 = fabsf(ppb[(8 + seg * 3 + 1) * NK + k]);
    const float r2 = fabsf(ppb[(8 + seg * 3 + 2) * NK + k]);
    const float rn = fabsf(ppb[(8 + nseg * 3 + 0) * NK + k]);
    const float w1 = fabsf(ppb[(20 + seg * 2 + 0) * NK + k]);
    const float w2 = fabsf(ppb[(20 + seg * 2 + 1) * NK + k]);

    // cos/sin of control radians, per segment (rotations of (CT,ST) by seg*90deg)
    const float c0x[4] = { 1.f, 0.f, -1.f,  0.f };
    const float c0y[4] = { 0.f, 1.f,  0.f, -1.f };
    const float c1x[4] = {  CT, -ST, -CT,  ST };
    const float c1y[4] = {  ST,  CT, -ST, -CT };
    const float c2x[4] = {  ST, -CT, -ST,  CT };
    const float c2y[4] = {  CT,  ST, -CT, -ST };

    const float P0x = c0x[seg] * r0,  P0y = c0y[seg] * r0;
    const float P1x = c1x[seg] * r1,  P1y = c1y[seg] * r1;
    const float P2x = c2x[seg] * r2,  P2y = c2y[seg] * r2;
    const float P3x = c0x[nseg] * rn, P3y = c0y[nseg] * rn;

    #pragma unroll
    for (int j = 0; j < 16; ++j) {
        const float t  = (float)j * 0.0625f;    // linspace(0,1,16,endpoint=False)
        const float u  = 1.f - t;
        const float b0 = u * u * u;
        const float b1 = 3.f * u * u * t;
        const float b2 = 3.f * u * t * t;
        const float b3 = t * t * t;
        const float wb1 = w1 * b1, wb2 = w2 * b2;
        const float inv = __builtin_amdgcn_rcpf(b0 + wb1 + wb2 + b3);
        const int s = seg * 16 + j;
        wcurve[(b * NS + s) * NK + k] = make_float2(
            (P0x * b0 + P1x * wb1 + P2x * wb2 + P3x * b3) * inv,
            (P0y * b0 + P1y * wb1 + P2y * wb2 + P3y * b3) * inv);
    }
}

// ---------- Kernel B: per-point SDF + CSG layers ----------
__global__ __launch_bounds__(512, 8) void extrude_net_kernel(
    const float* __restrict__ pts,
    const float* __restrict__ pp,
    const float* __restrict__ Wint,
    const float* __restrict__ Uw,
    const float2* __restrict__ wcurve,
    float* __restrict__ out)
{
    // Phase-1 read is (uniform s, lane k) -> 8B/lane, 2 lanes/bank = conflict-free (m136).
    __shared__ __align__(16) float2 s_curve[NS][NK];  // 32 KB
    __shared__ float s_om[PPB][NK];                   // 2 KB : om = 1-occ = sigmoid(+150*sdf)

    const int tid  = threadIdx.x;
    const int lane = tid & 63;
    const int wv   = tid >> 6;                 // wave id = point slot (0..7)
    const int gpt  = blockIdx.x * PPB + wv;    // global point index in [0, B*M)
    const int b    = gpt >> 11;                // / 2048 (blocks never straddle batches)
    const float* __restrict__ ppb = pp + b * (28 * NK);

    // ---- Stage curve table: 2048 float4s, 4 per thread ----
    {
        const float4* __restrict__ src = (const float4*)wcurve + b * (NS * NK / 2);
        float4* dst = (float4*)&s_curve[0][0];
        #pragma unroll
        for (int i = 0; i < 4; ++i)
            dst[i * 512 + tid] = src[i * 512 + tid];
    }
    __syncthreads();

    // ---- Phase 1: per-primitive SDF; wave = one point, lane = primitive k ----
    const float ptx = pts[gpt * 3 + 0];
    const float pty = pts[gpt * 3 + 1];
    const float ptz = pts[gpt * 3 + 2];
    {
        const int k = lane;
        const float q0 = ppb[0 * NK + k], q1 = ppb[1 * NK + k];
        const float q2 = ppb[2 * NK + k], q3 = ppb[3 * NK + k];
        const float trx = ppb[4 * NK + k], try_ = ppb[5 * NK + k], trz = ppb[6 * NK + k];
        const float h   = ppb[7 * NK + k];

        const float px = ptx - trx, py = pty - try_, pz = ptz - trz;
        const float inv = __builtin_amdgcn_rsqf(q0 * q0 + q1 * q1 + q2 * q2 + q3 * q3 + 1e-8f);
        const float w  = q0 * inv;
        const float vx = -q1 * inv, vy = -q2 * inv, vz = -q3 * inv;
        // rotate by conjugate: pl = p + w*t2 + cross(v, t2), t2 = 2*cross(v, p)
        const float t2x = 2.f * (vy * pz - vz * py);
        const float t2y = 2.f * (vz * px - vx * pz);
        const float t2z = 2.f * (vx * py - vy * px);
        const float plx = px + w * t2x + (vy * t2z - vz * t2y);
        const float ply = py + w * t2y + (vz * t2x - vx * t2z);
        const float plz = pz + w * t2z + (vx * t2y - vy * t2x);

        const float2* __restrict__ col = &s_curve[0][k];  // col[s*NK] = sample s

        const float2 cfirst = col[0];
        float rx = cfirst.x - plx;
        float ry = cfirst.y - ply;
        const float r0x = rx, r0y = ry;
        bool  aflag = ry > 0.f;
        const bool flag0 = aflag;
        int   up = 0, dn = 0;
        float d2a = rx * rx + ry * ry;
        float d2b = 3.4e38f;
        // Linear s: ds_read_b64 with immediate offsets, no per-iter address math.
        #pragma unroll 9
        for (int s = 1; s < NS; ++s) {
            const float2 cn = col[s * NK];
            const float nx = cn.x - plx;
            const float ny = cn.y - ply;
            const float cr = rx * ny - ry * nx;     // isLeft(V_s, V_s+1, P)
            const bool  bflag = ny > 0.f;
            up += (!aflag && bflag && cr > 0.f) ? 1 : 0;   // upward crossing, P left of edge
            dn += (aflag && !bflag && cr < 0.f) ? 1 : 0;   // downward crossing, P right of edge
            const float d2 = nx * nx + ny * ny;
            if (s & 1) d2b = fminf(d2b, d2); else d2a = fminf(d2a, d2);
            aflag = bflag; rx = nx; ry = ny;
        }
        // wrap edge: V63 -> V0 (rel kept in registers)
        {
            const float cr = rx * r0y - ry * r0x;
            up += (!aflag && flag0 && cr > 0.f) ? 1 : 0;
            dn += (aflag && !flag0 && cr < 0.f) ? 1 : 0;
        }
        const int   wn    = up - dn;
        const float dmin  = sqrtf(fminf(d2a, d2b) + 1e-12f);
        // sum(atan2) over closed polygon = 2*pi*wn exactly; |winding|>0.5 <=> wn != 0
        const float sdf2d = (wn != 0) ? -dmin : dmin;
        const float dz    = fabsf(plz) - fabsf(h);
        const float mx    = fmaxf(sdf2d, dz);
        const float e1    = fmaxf(sdf2d, 0.f);
        const float e2    = fmaxf(dz, 0.f);
        const float sdf   = fminf(mx, 0.f) + sqrtf(e1 * e1 + e2 * e2 + 1e-12f);

        out[SDF_OFF + gpt * NK + k] = sdf;
        out[SUP_OFF + gpt * NK + k] = dmin;
        // om = 1 - sigmoid(-150*sdf) = sigmoid(+150*sdf); rcp(inf)=0 so extremes are safe
        s_om[wv][k] = __builtin_amdgcn_rcpf(1.f + exp2f(-sdf * L2E_150));
    }
    __syncthreads();

    // ---- Phase 2: intersection (softmax over k; logits -40*pre in [-40,0] so no max
    // tracking needed: exp2 range [2^-57.7, 1] is normal) + union (wave softmax over c) ----
    {
        const int c = lane;
        const float* __restrict__ Wb  = Wint + b * (NK * NC);
        const float* __restrict__ omw = s_om[wv];
        float srun = 0.f, trun = 0.f;
        #pragma unroll 8
        for (int kk = 0; kk < NK; ++kk) {
            const float om  = omw[kk];                       // LDS broadcast, imm offset
            const float pre = fmaf(-Wb[kk * NC + c], om, 1.f);
            const float e   = exp2f(pre * -L2E_40);
            srun += e;
            trun = fmaf(e, pre, trun);
        }
        const float inter = trun * __builtin_amdgcn_rcpf(srun);
        out[INTER_OFF + gpt * NC + c] = inter;

        // Union: softmax(pu*40)-weighted sum across the wave's 64 lanes
        const float pu = Uw[b * NC + c] * inter;
        float umax = pu;
        #pragma unroll
        for (int off = 32; off > 0; off >>= 1)
            umax = fmaxf(umax, __shfl_xor(umax, off, 64));
        const float e = exp2f((pu - umax) * L2E_40);
        float s1 = e, s2 = e * pu;
        #pragma unroll
        for (int off = 32; off > 0; off >>= 1) {
            s1 += __shfl_xor(s1, off, 64);
            s2 += __shfl_xor(s2, off, 64);
        }
        if (lane == 0) out[OCC_OFF + gpt] = s2 * __builtin_amdgcn_rcpf(s1);
    }
}

extern "C" void kernel_launch(void* const* d_in, const int* in_sizes, int n_in,
                              void* d_out, int out_size, void* d_ws, size_t ws_size,
                              hipStream_t stream) {
    const float* pts  = (const float*)d_in[0];
    const float* pp   = (const float*)d_in[1];
    const float* Wint = (const float*)d_in[2];
    const float* Uw   = (const float*)d_in[3];
    // d_in[4] = is_training (always 1 in this harness) -> training path hardcoded.
    float*  out    = (float*)d_out;
    float2* wcurve = (float2*)d_ws;   // 4*64*64 float2 = 128 KB scratch

    curve_table_kernel<<<NB, 256, 0, stream>>>(pp, wcurve);
    const int grid = (NB * NM) / PPB;          // 1024 blocks x 512 threads
    extrude_net_kernel<<<grid, 512, 0, stream>>>(pts, pp, Wint, Uw, wcurve, out);
}

// Round 4
// 92.960 us; speedup vs baseline: 1.0004x; 1.0004x over previous
//
#include <hip/hip_runtime.h>
#include <math.h>

// ExtrudeNet fused kernels for MI355X (gfx950) — round 4.
// B=4, M=2048 points, K=64 primitives, C=64, NSEG=4, SAMPLE_RATE=16 -> S=64 curve samples.
// Inputs (float32): pts (B,M,3), pp (B,28,K), Wint (B,K,C), Uw (B,C), is_training (int, always 1).
// Output (float32, concatenated): occupancies (B,M) | primitive_sdf (B,M,K) | inter (B,M,C) | support (B,M,K).
//
// R4 change vs R3 (R3 ~neutral at dur 93; kernel ~39 us vs ~12 us VALU-issue model ->
// shared-latency stall suspected in phase 2's 64 global Wint loads per lane):
//  - phase 2 reads Wb from LDS: after phase 1's barrier the 32 KB curve table is dead,
//    so the 16 KB Wb slab is staged into that same LDS region (coalesced float4 copy,
//    one extra barrier). Inner loop becomes ds_read_b32 (c%32 banks -> 2 lanes/bank, free).
//  - phase-1 unroll 9 -> 7 (63 = 7x9), leaner in-flight load set under the 64-VGPR cap.

#define NB 4
#define NM 2048
#define NK 64
#define NC 64
#define NS 64
#define PPB 8   // points per 512-thread block (1 wave per point)

// Offsets into flat output
#define OCC_OFF   0
#define SDF_OFF   8192        // NB*NM
#define INTER_OFF 532480      // 8192 + 524288
#define SUP_OFF   1056768     // 8192 + 2*524288

// theta = 2*pi/16 + atan(tan(2*pi/16)/3) = 0.5299027864949896 (double-accurate)
#define CT 0.86285621096f     // cos(theta)
#define ST 0.50544946275f     // sin(theta)

#define L2E_40  57.70780163555852f   // 40 * log2(e)
#define L2E_150 216.40425613334447f  // 150 * log2(e)

// ---------- Kernel A: per-batch rational-bezier curve tables into workspace ----------
// grid = 4 (one block per batch), block = 256 (wave = segment, lane = primitive k).
__global__ __launch_bounds__(256) void curve_table_kernel(
    const float* __restrict__ pp,
    float2* __restrict__ wcurve)   // [NB][NS][NK]
{
    const int b    = blockIdx.x;
    const int lane = threadIdx.x & 63;
    const int seg  = threadIdx.x >> 6;          // 0..3
    const int nseg = (seg + 1) & 3;
    const float* __restrict__ ppb = pp + b * (28 * NK);
    const int k = lane;

    const float r0 = fabsf(ppb[(8 + seg * 3 + 0) * NK + k]);
    const float r1 = fabsf(ppb[(8 + seg * 3 + 1) * NK + k]);
    const float r2 = fabsf(ppb[(8 + seg * 3 + 2) * NK + k]);
    const float rn = fabsf(ppb[(8 + nseg * 3 + 0) * NK + k]);
    const float w1 = fabsf(ppb[(20 + seg * 2 + 0) * NK + k]);
    const float w2 = fabsf(ppb[(20 + seg * 2 + 1) * NK + k]);

    // cos/sin of control radians, per segment (rotations of (CT,ST) by seg*90deg)
    const float c0x[4] = { 1.f, 0.f, -1.f,  0.f };
    const float c0y[4] = { 0.f, 1.f,  0.f, -1.f };
    const float c1x[4] = {  CT, -ST, -CT,  ST };
    const float c1y[4] = {  ST,  CT, -ST, -CT };
    const float c2x[4] = {  ST, -CT, -ST,  CT };
    const float c2y[4] = {  CT,  ST, -CT, -ST };

    const float P0x = c0x[seg] * r0,  P0y = c0y[seg] * r0;
    const float P1x = c1x[seg] * r1,  P1y = c1y[seg] * r1;
    const float P2x = c2x[seg] * r2,  P2y = c2y[seg] * r2;
    const float P3x = c0x[nseg] * rn, P3y = c0y[nseg] * rn;

    #pragma unroll
    for (int j = 0; j < 16; ++j) {
        const float t  = (float)j * 0.0625f;    // linspace(0,1,16,endpoint=False)
        const float u  = 1.f - t;
        const float b0 = u * u * u;
        const float b1 = 3.f * u * u * t;
        const float b2 = 3.f * u * t * t;
        const float b3 = t * t * t;
        const float wb1 = w1 * b1, wb2 = w2 * b2;
        const float inv = __builtin_amdgcn_rcpf(b0 + wb1 + wb2 + b3);
        const int s = seg * 16 + j;
        wcurve[(b * NS + s) * NK + k] = make_float2(
            (P0x * b0 + P1x * wb1 + P2x * wb2 + P3x * b3) * inv,
            (P0y * b0 + P1y * wb1 + P2y * wb2 + P3y * b3) * inv);
    }
}

// ---------- Kernel B: per-point SDF + CSG layers ----------
__global__ __launch_bounds__(512, 8) void extrude_net_kernel(
    const float* __restrict__ pts,
    const float* __restrict__ pp,
    const float* __restrict__ Wint,
    const float* __restrict__ Uw,
    const float2* __restrict__ wcurve,
    float* __restrict__ out)
{
    // Phase-1 read is (uniform s, lane k) -> 8B/lane, 2 lanes/bank = conflict-free (m136).
    // After phase 1 this region is reused to hold the 16 KB Wb slab for phase 2.
    __shared__ __align__(16) float2 s_curve[NS][NK];  // 32 KB
    __shared__ float s_om[PPB][NK];                   // 2 KB : om = 1-occ = sigmoid(+150*sdf)

    const int tid  = threadIdx.x;
    const int lane = tid & 63;
    const int wv   = tid >> 6;                 // wave id = point slot (0..7)
    const int gpt  = blockIdx.x * PPB + wv;    // global point index in [0, B*M)
    const int b    = gpt >> 11;                // / 2048 (blocks never straddle batches)
    const float* __restrict__ ppb = pp + b * (28 * NK);

    // ---- Stage curve table: 2048 float4s, 4 per thread ----
    {
        const float4* __restrict__ src = (const float4*)wcurve + b * (NS * NK / 2);
        float4* dst = (float4*)&s_curve[0][0];
        #pragma unroll
        for (int i = 0; i < 4; ++i)
            dst[i * 512 + tid] = src[i * 512 + tid];
    }
    __syncthreads();

    // ---- Phase 1: per-primitive SDF; wave = one point, lane = primitive k ----
    const float ptx = pts[gpt * 3 + 0];
    const float pty = pts[gpt * 3 + 1];
    const float ptz = pts[gpt * 3 + 2];
    {
        const int k = lane;
        const float q0 = ppb[0 * NK + k], q1 = ppb[1 * NK + k];
        const float q2 = ppb[2 * NK + k], q3 = ppb[3 * NK + k];
        const float trx = ppb[4 * NK + k], try_ = ppb[5 * NK + k], trz = ppb[6 * NK + k];
        const float h   = ppb[7 * NK + k];

        const float px = ptx - trx, py = pty - try_, pz = ptz - trz;
        const float inv = __builtin_amdgcn_rsqf(q0 * q0 + q1 * q1 + q2 * q2 + q3 * q3 + 1e-8f);
        const float w  = q0 * inv;
        const float vx = -q1 * inv, vy = -q2 * inv, vz = -q3 * inv;
        // rotate by conjugate: pl = p + w*t2 + cross(v, t2), t2 = 2*cross(v, p)
        const float t2x = 2.f * (vy * pz - vz * py);
        const float t2y = 2.f * (vz * px - vx * pz);
        const float t2z = 2.f * (vx * py - vy * px);
        const float plx = px + w * t2x + (vy * t2z - vz * t2y);
        const float ply = py + w * t2y + (vz * t2x - vx * t2z);
        const float plz = pz + w * t2z + (vx * t2y - vy * t2x);

        const float2* __restrict__ col = &s_curve[0][k];  // col[s*NK] = sample s

        const float2 cfirst = col[0];
        float rx = cfirst.x - plx;
        float ry = cfirst.y - ply;
        const float r0x = rx, r0y = ry;
        bool  aflag = ry > 0.f;
        const bool flag0 = aflag;
        int   up = 0, dn = 0;
        float d2a = rx * rx + ry * ry;
        float d2b = 3.4e38f;
        // Linear s: ds_read_b64 with immediate offsets, no per-iter address math.
        #pragma unroll 7
        for (int s = 1; s < NS; ++s) {
            const float2 cn = col[s * NK];
            const float nx = cn.x - plx;
            const float ny = cn.y - ply;
            const float cr = rx * ny - ry * nx;     // isLeft(V_s, V_s+1, P)
            const bool  bflag = ny > 0.f;
            up += (!aflag && bflag && cr > 0.f) ? 1 : 0;   // upward crossing, P left of edge
            dn += (aflag && !bflag && cr < 0.f) ? 1 : 0;   // downward crossing, P right of edge
            const float d2 = nx * nx + ny * ny;
            if (s & 1) d2b = fminf(d2b, d2); else d2a = fminf(d2a, d2);
            aflag = bflag; rx = nx; ry = ny;
        }
        // wrap edge: V63 -> V0 (rel kept in registers)
        {
            const float cr = rx * r0y - ry * r0x;
            up += (!aflag && flag0 && cr > 0.f) ? 1 : 0;
            dn += (aflag && !flag0 && cr < 0.f) ? 1 : 0;
        }
        const int   wn    = up - dn;
        const float dmin  = sqrtf(fminf(d2a, d2b) + 1e-12f);
        // sum(atan2) over closed polygon = 2*pi*wn exactly; |winding|>0.5 <=> wn != 0
        const float sdf2d = (wn != 0) ? -dmin : dmin;
        const float dz    = fabsf(plz) - fabsf(h);
        const float mx    = fmaxf(sdf2d, dz);
        const float e1    = fmaxf(sdf2d, 0.f);
        const float e2    = fmaxf(dz, 0.f);
        const float sdf   = fminf(mx, 0.f) + sqrtf(e1 * e1 + e2 * e2 + 1e-12f);

        out[SDF_OFF + gpt * NK + k] = sdf;
        out[SUP_OFF + gpt * NK + k] = dmin;
        // om = 1 - sigmoid(-150*sdf) = sigmoid(+150*sdf); rcp(inf)=0 so extremes are safe
        s_om[wv][k] = __builtin_amdgcn_rcpf(1.f + exp2f(-sdf * L2E_150));
    }
    __syncthreads();   // phase-1 LDS reads complete -> curve region is dead

    // ---- Stage Wb (16 KB) into the dead curve region: 1024 float4s, 2 per thread ----
    {
        const float4* __restrict__ wsrc = (const float4*)(Wint + b * (NK * NC));
        float4* wdst = (float4*)&s_curve[0][0];
        wdst[tid]       = wsrc[tid];
        wdst[tid + 512] = wsrc[tid + 512];
    }
    __syncthreads();

    // ---- Phase 2: intersection (softmax over k; logits -40*pre in [-40,0] so no max
    // tracking needed: exp2 range [2^-57.7, 1] is normal) + union (wave softmax over c) ----
    {
        const int c = lane;
        const float* __restrict__ WbL = (const float*)&s_curve[0][0];  // [NK][NC] in LDS
        const float* __restrict__ omw = s_om[wv];
        float srun = 0.f, trun = 0.f;
        #pragma unroll 8
        for (int kk = 0; kk < NK; ++kk) {
            const float om  = omw[kk];                       // LDS broadcast, imm offset
            const float pre = fmaf(-WbL[kk * NC + c], om, 1.f);  // bank c%32: conflict-free
            const float e   = exp2f(pre * -L2E_40);
            srun += e;
            trun = fmaf(e, pre, trun);
        }
        const float inter = trun * __builtin_amdgcn_rcpf(srun);
        out[INTER_OFF + gpt * NC + c] = inter;

        // Union: softmax(pu*40)-weighted sum across the wave's 64 lanes
        const float pu = Uw[b * NC + c] * inter;
        float umax = pu;
        #pragma unroll
        for (int off = 32; off > 0; off >>= 1)
            umax = fmaxf(umax, __shfl_xor(umax, off, 64));
        const float e = exp2f((pu - umax) * L2E_40);
        float s1 = e, s2 = e * pu;
        #pragma unroll
        for (int off = 32; off > 0; off >>= 1) {
            s1 += __shfl_xor(s1, off, 64);
            s2 += __shfl_xor(s2, off, 64);
        }
        if (lane == 0) out[OCC_OFF + gpt] = s2 * __builtin_amdgcn_rcpf(s1);
    }
}

extern "C" void kernel_launch(void* const* d_in, const int* in_sizes, int n_in,
                              void* d_out, int out_size, void* d_ws, size_t ws_size,
                              hipStream_t stream) {
    const float* pts  = (const float*)d_in[0];
    const float* pp   = (const float*)d_in[1];
    const float* Wint = (const float*)d_in[2];
    const float* Uw   = (const float*)d_in[3];
    // d_in[4] = is_training (always 1 in this harness) -> training path hardcoded.
    float*  out    = (float*)d_out;
    float2* wcurve = (float2*)d_ws;   // 4*64*64 float2 = 128 KB scratch

    curve_table_kernel<<<NB, 256, 0, stream>>>(pp, wcurve);
    const int grid = (NB * NM) / PPB;          // 1024 blocks x 512 threads
    extrude_net_kernel<<<grid, 512, 0, stream>>>(pts, pp, Wint, Uw, wcurve, out);
}

// Round 5
// 88.856 us; speedup vs baseline: 1.0466x; 1.0462x over previous
//
#include <hip/hip_runtime.h>
#include <math.h>

// ExtrudeNet fused kernels for MI355X (gfx950) — round 5.
// B=4, M=2048 points, K=64 primitives, C=64, NSEG=4, SAMPLE_RATE=16 -> S=64 curve samples.
// Inputs (float32): pts (B,M,3), pp (B,28,K), Wint (B,K,C), Uw (B,C), is_training (int, always 1).
// Output (float32, concatenated): occupancies (B,M) | primitive_sdf (B,M,K) | inter (B,M,C) | support (B,M,K).
//
// R5 theory: kernel stuck at ~42 us across R2-R4 (insensitive to instruction hoists, occupancy,
// memory source) -> emitted-code bloat in the phase-1 crossing tests (R1 back-calc: compiler
// emits ~2x source-level VALU count; '&&' short-circuit + carried bools + (512,8) VGPR cap
// risk cndmask/exec-mask chains and scratch spills). R5: branchless '&' bools, single wn
// accumulator, FULL unroll (imm ds offsets, no loop arith), 256-thr blocks with no VGPR cap.

#define NB 4
#define NM 2048
#define NK 64
#define NC 64
#define NS 64
#define PPB 4   // points per 256-thread block (1 wave per point)

// Offsets into flat output
#define OCC_OFF   0
#define SDF_OFF   8192        // NB*NM
#define INTER_OFF 532480      // 8192 + 524288
#define SUP_OFF   1056768     // 8192 + 2*524288

// theta = 2*pi/16 + atan(tan(2*pi/16)/3) = 0.5299027864949896 (double-accurate)
#define CT 0.86285621096f     // cos(theta)
#define ST 0.50544946275f     // sin(theta)

#define L2E_40  57.70780163555852f   // 40 * log2(e)
#define L2E_150 216.40425613334447f  // 150 * log2(e)

// ---------- Kernel A: per-batch rational-bezier curve tables into workspace ----------
// grid = 4 (one block per batch), block = 256 (wave = segment, lane = primitive k).
__global__ __launch_bounds__(256) void curve_table_kernel(
    const float* __restrict__ pp,
    float2* __restrict__ wcurve)   // [NB][NS][NK]
{
    const int b    = blockIdx.x;
    const int lane = threadIdx.x & 63;
    const int seg  = threadIdx.x >> 6;          // 0..3
    const int nseg = (seg + 1) & 3;
    const float* __restrict__ ppb = pp + b * (28 * NK);
    const int k = lane;

    const float r0 = fabsf(ppb[(8 + seg * 3 + 0) * NK + k]);
    const float r1 = fabsf(ppb[(8 + seg * 3 + 1) * NK + k]);
    const float r2 = fabsf(ppb[(8 + seg * 3 + 2) * NK + k]);
    const float rn = fabsf(ppb[(8 + nseg * 3 + 0) * NK + k]);
    const float w1 = fabsf(ppb[(20 + seg * 2 + 0) * NK + k]);
    const float w2 = fabsf(ppb[(20 + seg * 2 + 1) * NK + k]);

    // cos/sin of control radians, per segment (rotations of (CT,ST) by seg*90deg)
    const float c0x[4] = { 1.f, 0.f, -1.f,  0.f };
    const float c0y[4] = { 0.f, 1.f,  0.f, -1.f };
    const float c1x[4] = {  CT, -ST, -CT,  ST };
    const float c1y[4] = {  ST,  CT, -ST, -CT };
    const float c2x[4] = {  ST, -CT, -ST,  CT };
    const float c2y[4] = {  CT,  ST, -CT, -ST };

    const float P0x = c0x[seg] * r0,  P0y = c0y[seg] * r0;
    const float P1x = c1x[seg] * r1,  P1y = c1y[seg] * r1;
    const float P2x = c2x[seg] * r2,  P2y = c2y[seg] * r2;
    const float P3x = c0x[nseg] * rn, P3y = c0y[nseg] * rn;

    #pragma unroll
    for (int j = 0; j < 16; ++j) {
        const float t  = (float)j * 0.0625f;    // linspace(0,1,16,endpoint=False)
        const float u  = 1.f - t;
        const float b0 = u * u * u;
        const float b1 = 3.f * u * u * t;
        const float b2 = 3.f * u * t * t;
        const float b3 = t * t * t;
        const float wb1 = w1 * b1, wb2 = w2 * b2;
        const float inv = __builtin_amdgcn_rcpf(b0 + wb1 + wb2 + b3);
        const int s = seg * 16 + j;
        wcurve[(b * NS + s) * NK + k] = make_float2(
            (P0x * b0 + P1x * wb1 + P2x * wb2 + P3x * b3) * inv,
            (P0y * b0 + P1y * wb1 + P2y * wb2 + P3y * b3) * inv);
    }
}

// ---------- Kernel B: per-point SDF + CSG layers ----------
__global__ __launch_bounds__(256) void extrude_net_kernel(
    const float* __restrict__ pts,
    const float* __restrict__ pp,
    const float* __restrict__ Wint,
    const float* __restrict__ Uw,
    const float2* __restrict__ wcurve,
    float* __restrict__ out)
{
    // Phase-1 read is (uniform s, lane k) -> 8B/lane float2. After phase 1 this
    // region is reused to hold the 16 KB Wb slab for phase 2.
    __shared__ __align__(16) float2 s_curve[NS][NK];  // 32 KB
    __shared__ float s_om[PPB][NK];                   // 1 KB : om = 1-occ = sigmoid(+150*sdf)

    const int tid  = threadIdx.x;
    const int lane = tid & 63;
    const int wv   = tid >> 6;                 // wave id = point slot (0..3)
    const int gpt  = blockIdx.x * PPB + wv;    // global point index in [0, B*M)
    const int b    = gpt >> 11;                // / 2048 (blocks never straddle batches)
    const float* __restrict__ ppb = pp + b * (28 * NK);

    // ---- Stage curve table: 2048 float4s, 8 per thread ----
    {
        const float4* __restrict__ src = (const float4*)wcurve + b * (NS * NK / 2);
        float4* dst = (float4*)&s_curve[0][0];
        #pragma unroll
        for (int i = 0; i < 8; ++i)
            dst[i * 256 + tid] = src[i * 256 + tid];
    }
    __syncthreads();

    // ---- Phase 1: per-primitive SDF; wave = one point, lane = primitive k ----
    const float ptx = pts[gpt * 3 + 0];
    const float pty = pts[gpt * 3 + 1];
    const float ptz = pts[gpt * 3 + 2];
    {
        const int k = lane;
        const float q0 = ppb[0 * NK + k], q1 = ppb[1 * NK + k];
        const float q2 = ppb[2 * NK + k], q3 = ppb[3 * NK + k];
        const float trx = ppb[4 * NK + k], try_ = ppb[5 * NK + k], trz = ppb[6 * NK + k];
        const float h   = ppb[7 * NK + k];

        const float px = ptx - trx, py = pty - try_, pz = ptz - trz;
        const float inv = __builtin_amdgcn_rsqf(q0 * q0 + q1 * q1 + q2 * q2 + q3 * q3 + 1e-8f);
        const float w  = q0 * inv;
        const float vx = -q1 * inv, vy = -q2 * inv, vz = -q3 * inv;
        // rotate by conjugate: pl = p + w*t2 + cross(v, t2), t2 = 2*cross(v, p)
        const float t2x = 2.f * (vy * pz - vz * py);
        const float t2y = 2.f * (vz * px - vx * pz);
        const float t2z = 2.f * (vx * py - vy * px);
        const float plx = px + w * t2x + (vy * t2z - vz * t2y);
        const float ply = py + w * t2y + (vz * t2x - vx * t2z);
        const float plz = pz + w * t2z + (vx * t2y - vy * t2x);

        const float2* __restrict__ col = &s_curve[0][k];  // col[s*NK] = sample s

        const float2 cfirst = col[0];
        float rx = cfirst.x - plx;
        float ry = cfirst.y - ply;
        const float r0x = rx, r0y = ry;
        bool apos = ry > 0.f;
        const bool pos0 = apos;
        int   wn  = 0;
        float d2a = rx * rx + ry * ry;
        float d2b = 3.4e38f;
        // FULL unroll: every ds_read_b64 offset is a compile-time immediate,
        // zero loop/address arithmetic. Branchless '&' on bools (no short-circuit).
        #pragma unroll
        for (int s = 1; s < NS; ++s) {
            const float2 cn = col[s * NK];
            const float nx = cn.x - plx;
            const float ny = cn.y - ply;
            const float cr = rx * ny - ry * nx;     // isLeft(V_s, V_s+1, P)
            const bool bpos = ny > 0.f;
            const bool cpos = cr > 0.f;
            const bool cneg = cr < 0.f;
            wn += ((!apos) & bpos & cpos) ? 1 : 0;  // upward crossing, P left of edge
            wn -= (apos & (!bpos) & cneg) ? 1 : 0;  // downward crossing, P right of edge
            const float d2 = nx * nx + ny * ny;
            if (s & 1) d2b = fminf(d2b, d2); else d2a = fminf(d2a, d2);
            apos = bpos; rx = nx; ry = ny;
        }
        // wrap edge: V63 -> V0 (rel kept in registers)
        {
            const float cr = rx * r0y - ry * r0x;
            wn += ((!apos) & pos0 & (cr > 0.f)) ? 1 : 0;
            wn -= (apos & (!pos0) & (cr < 0.f)) ? 1 : 0;
        }
        const float dmin  = sqrtf(fminf(d2a, d2b) + 1e-12f);
        // sum(atan2) over closed polygon = 2*pi*wn exactly; |winding|>0.5 <=> wn != 0
        const float sdf2d = (wn != 0) ? -dmin : dmin;
        const float dz    = fabsf(plz) - fabsf(h);
        const float mx    = fmaxf(sdf2d, dz);
        const float e1    = fmaxf(sdf2d, 0.f);
        const float e2    = fmaxf(dz, 0.f);
        const float sdf   = fminf(mx, 0.f) + sqrtf(e1 * e1 + e2 * e2 + 1e-12f);

        out[SDF_OFF + gpt * NK + k] = sdf;
        out[SUP_OFF + gpt * NK + k] = dmin;
        // om = 1 - sigmoid(-150*sdf) = sigmoid(+150*sdf); rcp(inf)=0 so extremes are safe
        s_om[wv][k] = __builtin_amdgcn_rcpf(1.f + exp2f(-sdf * L2E_150));
    }
    __syncthreads();   // phase-1 LDS reads complete -> curve region is dead

    // ---- Stage Wb (16 KB) into the dead curve region: 1024 float4s, 4 per thread ----
    {
        const float4* __restrict__ wsrc = (const float4*)(Wint + b * (NK * NC));
        float4* wdst = (float4*)&s_curve[0][0];
        #pragma unroll
        for (int i = 0; i < 4; ++i)
            wdst[i * 256 + tid] = wsrc[i * 256 + tid];
    }
    __syncthreads();

    // ---- Phase 2: intersection (softmax over k; logits -40*pre in [-40,0] so no max
    // tracking needed: exp2 range [2^-57.7, 1] is normal) + union (wave softmax over c) ----
    {
        const int c = lane;
        const float* __restrict__ WbL = (const float*)&s_curve[0][0];  // [NK][NC] in LDS
        const float* __restrict__ omw = s_om[wv];
        float srun = 0.f, trun = 0.f;
        #pragma unroll
        for (int kk = 0; kk < NK; ++kk) {
            const float om  = omw[kk];                       // LDS broadcast, imm offset
            const float pre = fmaf(-WbL[kk * NC + c], om, 1.f);  // bank c%32
            const float e   = exp2f(pre * -L2E_40);
            srun += e;
            trun = fmaf(e, pre, trun);
        }
        const float inter = trun * __builtin_amdgcn_rcpf(srun);
        out[INTER_OFF + gpt * NC + c] = inter;

        // Union: softmax(pu*40)-weighted sum across the wave's 64 lanes
        const float pu = Uw[b * NC + c] * inter;
        float umax = pu;
        #pragma unroll
        for (int off = 32; off > 0; off >>= 1)
            umax = fmaxf(umax, __shfl_xor(umax, off, 64));
        const float e = exp2f((pu - umax) * L2E_40);
        float s1 = e, s2 = e * pu;
        #pragma unroll
        for (int off = 32; off > 0; off >>= 1) {
            s1 += __shfl_xor(s1, off, 64);
            s2 += __shfl_xor(s2, off, 64);
        }
        if (lane == 0) out[OCC_OFF + gpt] = s2 * __builtin_amdgcn_rcpf(s1);
    }
}

extern "C" void kernel_launch(void* const* d_in, const int* in_sizes, int n_in,
                              void* d_out, int out_size, void* d_ws, size_t ws_size,
                              hipStream_t stream) {
    const float* pts  = (const float*)d_in[0];
    const float* pp   = (const float*)d_in[1];
    const float* Wint = (const float*)d_in[2];
    const float* Uw   = (const float*)d_in[3];
    // d_in[4] = is_training (always 1 in this harness) -> training path hardcoded.
    float*  out    = (float*)d_out;
    float2* wcurve = (float2*)d_ws;   // 4*64*64 float2 = 128 KB scratch

    curve_table_kernel<<<NB, 256, 0, stream>>>(pp, wcurve);
    const int grid = (NB * NM) / PPB;          // 2048 blocks x 256 threads
    extrude_net_kernel<<<grid, 256, 0, stream>>>(pts, pp, Wint, Uw, wcurve, out);
}